// Round 3
// baseline (354.668 us; speedup 1.0000x reference)
//
#include <hip/hip_runtime.h>

// GAT layer, CSR formulation (no float atomics):
//   Kd  detect edge_index width (int32 vs int64)
//   K1  GEMM X@W.T -> H  (64-row tile, 4x4 micro-tile/thread; fused s_src/s_dst)
//   K2  e=lrelu(s_src[src]+s_dst[dst]); global max (atomicMax); count[dst]++
//   S1-S3  exclusive scan of counts -> rowstart, cursor
//   KF  bucket edges: pos=atomicAdd(cursor[dst]); csr_src[pos]=src; csr_w[pos]=exp(e-max)
//   KA  one wave per dst, 4 edges x 16 lanes x float4; out=acc/(denom+1e-12). No atomics.

#define N_NODES 50000
#define N_EDGES 800000
#define IN_DIM  128
#define OUT_DIM 64
#define NEG_SLOPE 0.2f
#define NBLK_SCAN ((N_NODES + 255) / 256)   // 196

// workspace layout (4-byte element offsets; d_ws is 256B-aligned)
#define WS_H      0                          // float N*64
#define WS_SSRC   (N_NODES * OUT_DIM)        // float N
#define WS_SDST   (WS_SSRC + N_NODES)        // float N
#define WS_E      (WS_SDST + N_NODES)        // float E
#define WS_COUNT  (WS_E + N_EDGES)           // int N      (memset 0 with maxkey)
#define WS_MAXKEY (WS_COUNT + N_NODES)       // uint 1
#define WS_FLAG   (WS_MAXKEY + 1)            // int 1
#define WS_ROWST  (WS_FLAG + 1)              // int N
#define WS_CURS   (WS_ROWST + N_NODES)       // int N
#define WS_BSUM   (WS_CURS + N_NODES)        // int 256
#define WS_CSRS   (WS_BSUM + 256)            // int E
#define WS_CSRW   (WS_CSRS + N_EDGES)        // float E

// ---- order-preserving float<->uint key for atomicMax on mixed-sign floats ----
__device__ __forceinline__ unsigned int fkey(float f) {
    unsigned int b = __float_as_uint(f);
    return b ^ (((int)b >> 31) | 0x80000000u);
}
__device__ __forceinline__ float funkey(unsigned int u) {
    unsigned int b = (u & 0x80000000u) ? (u ^ 0x80000000u) : ~u;
    return __uint_as_float(b);
}

// uniform-branch edge index fetch (int32 or int64 storage)
__device__ __forceinline__ int eidx(const void* ei, int use64, long long i) {
    return use64 ? (int)((const long long*)ei)[i] : ((const int*)ei)[i];
}

// Kd: int64 iff high words of first 64 putative int64 values are all zero
__global__ void detect_kernel(const unsigned int* __restrict__ ei32, int* __restrict__ flag) {
    unsigned int v = ei32[2 * threadIdx.x + 1];
    unsigned long long nz = __ballot(v != 0u);
    if (threadIdx.x == 0) *flag = (nz == 0ULL) ? 1 : 0;
}

// K1: H = X @ W.T + per-node attention scalars.
// 256 thr: cg = t&15 (4 cols), rg = t>>4 (4 rows) -> 4x4 micro-tile, 64-row block tile.
// sWt k-major [k][col] (W read b128, 2-way = free). sX k-major [k][row] pad 65
// (inner X reads hit banks {b,b+4,b+8,b+12} -> conflict-free); staged in 2 k-chunks.
__global__ __launch_bounds__(256) void gemm_kernel(
        const float* __restrict__ X, const float* __restrict__ W,
        const float* __restrict__ a_src, const float* __restrict__ a_dst,
        float* __restrict__ H, float* __restrict__ s_src, float* __restrict__ s_dst) {
    __shared__ float sWt[IN_DIM][OUT_DIM];   // 32 KB
    __shared__ float sX[64][65];             // 16.6 KB; total 49.4 KB -> 3 blocks/CU
    const int t = threadIdx.x;
    const int row0 = blockIdx.x * 64;
    const int cg = t & 15;
    const int rg = t >> 4;

    // stage W transposed: thread (col = i&63, k4 = i>>6); LDS writes conflict-free
    for (int i = t; i < 64 * 32; i += 256) {
        int col = i & 63, k4 = i >> 6;
        float4 w = reinterpret_cast<const float4*>(W)[col * 32 + k4];
        sWt[4 * k4 + 0][col] = w.x;
        sWt[4 * k4 + 1][col] = w.y;
        sWt[4 * k4 + 2][col] = w.z;
        sWt[4 * k4 + 3][col] = w.w;
    }

    float acc[4][4];
    #pragma unroll
    for (int i = 0; i < 4; ++i)
        #pragma unroll
        for (int j = 0; j < 4; ++j) acc[i][j] = 0.f;

    #pragma unroll
    for (int kk = 0; kk < 2; ++kk) {
        const int kb = kk * 64;
        __syncthreads();   // kk=0: W staged; kk=1: chunk-0 readers done
        // stage X chunk: thread (k4 = i&15, row = i>>4); writes ~2-way (free)
        for (int i = t; i < 64 * 16; i += 256) {
            int k4 = i & 15, row = i >> 4;
            int grow = row0 + row;
            float4 x = make_float4(0.f, 0.f, 0.f, 0.f);
            if (grow < N_NODES)
                x = reinterpret_cast<const float4*>(X)[(size_t)grow * 32 + (kb >> 2) + k4];
            sX[4 * k4 + 0][row] = x.x;
            sX[4 * k4 + 1][row] = x.y;
            sX[4 * k4 + 2][row] = x.z;
            sX[4 * k4 + 3][row] = x.w;
        }
        __syncthreads();
        #pragma unroll 4
        for (int k = 0; k < 64; ++k) {
            float4 wv = *reinterpret_cast<const float4*>(&sWt[kb + k][cg * 4]);  // 16 FMA per b128
            #pragma unroll
            for (int i = 0; i < 4; ++i) {
                float xv = sX[k][rg * 4 + i];
                acc[i][0] += xv * wv.x; acc[i][1] += xv * wv.y;
                acc[i][2] += xv * wv.z; acc[i][3] += xv * wv.w;
            }
        }
    }

    float4 as = *reinterpret_cast<const float4*>(&a_src[cg * 4]);
    float4 ad = *reinterpret_cast<const float4*>(&a_dst[cg * 4]);
    #pragma unroll
    for (int i = 0; i < 4; ++i) {
        float ps = acc[i][0] * as.x + acc[i][1] * as.y + acc[i][2] * as.z + acc[i][3] * as.w;
        float pd = acc[i][0] * ad.x + acc[i][1] * ad.y + acc[i][2] * ad.z + acc[i][3] * ad.w;
        #pragma unroll
        for (int off = 1; off < 16; off <<= 1) {   // reduce across the 16 col-groups
            ps += __shfl_xor(ps, off);
            pd += __shfl_xor(pd, off);
        }
        int row = row0 + rg * 4 + i;
        if (row < N_NODES) {
            *reinterpret_cast<float4*>(&H[(size_t)row * OUT_DIM + cg * 4]) =
                make_float4(acc[i][0], acc[i][1], acc[i][2], acc[i][3]);
            if (cg == 0) { s_src[row] = ps; s_dst[row] = pd; }
        }
    }
}

// K2: e = leaky_relu(s_src[src]+s_dst[dst]); global max; degree histogram
__global__ __launch_bounds__(256) void edge_max_count_kernel(
        const void* __restrict__ ei, const int* __restrict__ flag,
        const float* __restrict__ s_src, const float* __restrict__ s_dst,
        float* __restrict__ e, unsigned int* __restrict__ maxkey, int* __restrict__ count) {
    const int use64 = *flag;
    long long i = (long long)blockIdx.x * blockDim.x + threadIdx.x;
    float v = -3.402823466e38f;
    if (i < N_EDGES) {
        int s = eidx(ei, use64, i);
        int d = eidx(ei, use64, N_EDGES + i);
        v = s_src[s] + s_dst[d];
        v = (v >= 0.f) ? v : NEG_SLOPE * v;
        e[i] = v;
        atomicAdd(&count[d], 1);
    }
    #pragma unroll
    for (int off = 32; off; off >>= 1) v = fmaxf(v, __shfl_xor(v, off));
    if ((threadIdx.x & 63) == 0) atomicMax(maxkey, fkey(v));
}

// ---- hierarchical exclusive scan of count[N] -> rowstart, cursor ----
__device__ __forceinline__ int block_excl_scan_256(int x, int* lds4) {
    const int lane = threadIdx.x & 63;
    const int wid  = threadIdx.x >> 6;
    int incl = x;
    #pragma unroll
    for (int off = 1; off < 64; off <<= 1) {
        int n = __shfl_up(incl, off);
        if (lane >= off) incl += n;
    }
    if (lane == 63) lds4[wid] = incl;
    __syncthreads();
    if (threadIdx.x == 0) {
        int s = 0;
        #pragma unroll
        for (int w = 0; w < 4; ++w) { int tv = lds4[w]; lds4[w] = s; s += tv; }
    }
    __syncthreads();
    return lds4[wid] + incl - x;
}

__global__ __launch_bounds__(256) void scan1_kernel(const int* __restrict__ count,
                                                    int* __restrict__ blockSum) {
    int i = blockIdx.x * 256 + threadIdx.x;
    int v = (i < N_NODES) ? count[i] : 0;
    #pragma unroll
    for (int off = 32; off; off >>= 1) v += __shfl_xor(v, off);
    __shared__ int lds4[4];
    if ((threadIdx.x & 63) == 0) lds4[threadIdx.x >> 6] = v;
    __syncthreads();
    if (threadIdx.x == 0) blockSum[blockIdx.x] = lds4[0] + lds4[1] + lds4[2] + lds4[3];
}

__global__ __launch_bounds__(256) void scan2_kernel(int* __restrict__ blockSum) {
    __shared__ int lds4[4];
    int v = (threadIdx.x < NBLK_SCAN) ? blockSum[threadIdx.x] : 0;
    int ex = block_excl_scan_256(v, lds4);
    if (threadIdx.x < NBLK_SCAN) blockSum[threadIdx.x] = ex;
}

__global__ __launch_bounds__(256) void scan3_kernel(const int* __restrict__ count,
                                                    const int* __restrict__ blockOfs,
                                                    int* __restrict__ rowstart,
                                                    int* __restrict__ cursor) {
    __shared__ int lds4[4];
    int i = blockIdx.x * 256 + threadIdx.x;
    int v = (i < N_NODES) ? count[i] : 0;
    int ex = block_excl_scan_256(v, lds4) + blockOfs[blockIdx.x];
    if (i < N_NODES) { rowstart[i] = ex; cursor[i] = ex; }
}

// KF: bucket edges into CSR order, computing exp(e - max) on the way
__global__ __launch_bounds__(256) void fill_kernel(
        const void* __restrict__ ei, const int* __restrict__ flag,
        const float* __restrict__ e, const unsigned int* __restrict__ maxkey,
        int* __restrict__ cursor, int* __restrict__ csr_src, float* __restrict__ csr_w) {
    const int use64 = *flag;
    const float m = funkey(*maxkey);
    long long i = (long long)blockIdx.x * blockDim.x + threadIdx.x;
    if (i >= N_EDGES) return;
    int s = eidx(ei, use64, i);
    int d = eidx(ei, use64, N_EDGES + i);
    float ex = expf(e[i] - m);
    int pos = atomicAdd(&cursor[d], 1);
    csr_src[pos] = s;
    csr_w[pos] = ex;
}

// KA: one wave per dst. lane = (eo = lane>>4, cg = lane&15): 4 edges in flight,
// each edge's 256B H-row gathered as 16 x float4. Reduce over eo via shfl_xor.
__global__ __launch_bounds__(256) void aggregate_kernel(
        const float* __restrict__ H, const int* __restrict__ count,
        const int* __restrict__ rowstart, const int* __restrict__ csr_src,
        const float* __restrict__ csr_w, float* __restrict__ out) {
    const int lane = threadIdx.x & 63;
    const int eo   = lane >> 4;
    const int cg   = lane & 15;
    const int dst  = blockIdx.x * 4 + (threadIdx.x >> 6);
    if (dst >= N_NODES) return;
    const int rs  = rowstart[dst];
    const int deg = count[dst];
    float4 acc = make_float4(0.f, 0.f, 0.f, 0.f);
    float denom = 0.f;
    for (int j = 0; j < deg; j += 4) {
        int jj = j + eo;
        int s = 0;
        float w = 0.f;
        if (jj < deg) {
            s = csr_src[rs + jj];   // 16-lane broadcast
            w = csr_w[rs + jj];
        }
        float4 h = *reinterpret_cast<const float4*>(&H[(size_t)s * OUT_DIM + cg * 4]);
        acc.x += w * h.x; acc.y += w * h.y; acc.z += w * h.z; acc.w += w * h.w;
        denom += w;
    }
    acc.x += __shfl_xor(acc.x, 16); acc.y += __shfl_xor(acc.y, 16);
    acc.z += __shfl_xor(acc.z, 16); acc.w += __shfl_xor(acc.w, 16);
    denom += __shfl_xor(denom, 16);
    acc.x += __shfl_xor(acc.x, 32); acc.y += __shfl_xor(acc.y, 32);
    acc.z += __shfl_xor(acc.z, 32); acc.w += __shfl_xor(acc.w, 32);
    denom += __shfl_xor(denom, 32);
    if (eo == 0) {
        float inv = 1.f / (denom + 1e-12f);
        *reinterpret_cast<float4*>(&out[(size_t)dst * OUT_DIM + cg * 4]) =
            make_float4(acc.x * inv, acc.y * inv, acc.z * inv, acc.w * inv);
    }
}

extern "C" void kernel_launch(void* const* d_in, const int* in_sizes, int n_in,
                              void* d_out, int out_size, void* d_ws, size_t ws_size,
                              hipStream_t stream) {
    const float* X     = (const float*)d_in[0];
    const void*  ei    = d_in[1];                 // [2,E] int32 or int64 (detected)
    const float* W     = (const float*)d_in[3];
    const float* a_src = (const float*)d_in[4];
    const float* a_dst = (const float*)d_in[5];
    float* out = (float*)d_out;

    float* ws      = (float*)d_ws;
    float* H       = ws + WS_H;
    float* s_src   = ws + WS_SSRC;
    float* s_dst   = ws + WS_SDST;
    float* e       = ws + WS_E;
    int*   count   = (int*)(ws + WS_COUNT);
    unsigned int* maxkey = (unsigned int*)(ws + WS_MAXKEY);
    int*   flag    = (int*)(ws + WS_FLAG);
    int*   rowst   = (int*)(ws + WS_ROWST);
    int*   cursor  = (int*)(ws + WS_CURS);
    int*   bsum    = (int*)(ws + WS_BSUM);
    int*   csr_src = (int*)(ws + WS_CSRS);
    float* csr_w   = ws + WS_CSRW;

    // count + maxkey are the only buffers needing zeros (adjacent -> one memset)
    hipMemsetAsync(count, 0, (size_t)(N_NODES + 1) * sizeof(int), stream);

    detect_kernel<<<1, 64, 0, stream>>>((const unsigned int*)ei, flag);
    gemm_kernel<<<(N_NODES + 63) / 64, 256, 0, stream>>>(X, W, a_src, a_dst, H, s_src, s_dst);
    edge_max_count_kernel<<<(N_EDGES + 255) / 256, 256, 0, stream>>>(ei, flag, s_src, s_dst, e, maxkey, count);
    scan1_kernel<<<NBLK_SCAN, 256, 0, stream>>>(count, bsum);
    scan2_kernel<<<1, 256, 0, stream>>>(bsum);
    scan3_kernel<<<NBLK_SCAN, 256, 0, stream>>>(count, bsum, rowst, cursor);
    fill_kernel<<<(N_EDGES + 255) / 256, 256, 0, stream>>>(ei, flag, e, maxkey, cursor, csr_src, csr_w);
    aggregate_kernel<<<(N_NODES + 3) / 4, 256, 0, stream>>>(H, count, rowst, csr_src, csr_w, out);
}

// Round 4
// 235.555 us; speedup vs baseline: 1.5057x; 1.5057x over previous
//
#include <hip/hip_runtime.h>

// GAT layer, CSR formulation, no single-address atomics:
//   Kd  detect edge_index width (int32 vs int64)
//   K1  GEMM X@W.T -> H  (64-row tile, 4x4 micro-tile/thread; fused s_src/s_dst)
//   K2  packed[i]=dst<<16|src; count[dst]++; per-block max -> blockmax[] (plain store)
//   KM  1-block reduce: gmax = max(blockmax)
//   S1-S3  exclusive scan of counts -> rowstart, cursor
//   KF  pos=atomicAdd(cursor[dst]); csr16[pos]=src  (ushort)
//   KA  one wave per dst, 4 edges x 16 lanes x float4; w recomputed from s_src/s_dst.

#define N_NODES 50000
#define N_EDGES 800000
#define IN_DIM  128
#define OUT_DIM 64
#define NEG_SLOPE 0.2f
#define NBLK_SCAN ((N_NODES + 255) / 256)   // 196
#define NBLK_E    (N_EDGES / 256)           // 3125 exact (800000 = 3125*256)

// workspace layout (4-byte element offsets; d_ws is 256B-aligned)
#define WS_H      0                          // float N*64
#define WS_SSRC   (N_NODES * OUT_DIM)        // float N
#define WS_SDST   (WS_SSRC + N_NODES)        // float N
#define WS_PACK   (WS_SDST + N_NODES)        // uint E
#define WS_COUNT  (WS_PACK + N_EDGES)        // int N   (memset 0)
#define WS_GMAX   (WS_COUNT + N_NODES)       // float 1
#define WS_FLAG   (WS_GMAX + 1)              // int 1
#define WS_ROWST  (WS_FLAG + 1)              // int N
#define WS_CURS   (WS_ROWST + N_NODES)       // int N
#define WS_BSUM   (WS_CURS + N_NODES)        // int 256
#define WS_BMAX   (WS_BSUM + 256)            // float NBLK_E
#define WS_CSR16  (WS_BMAX + NBLK_E)         // ushort E (E/2 float slots)

// uniform-branch edge index fetch (int32 or int64 storage)
__device__ __forceinline__ int eidx(const void* ei, int use64, long long i) {
    return use64 ? (int)((const long long*)ei)[i] : ((const int*)ei)[i];
}

// Kd: int64 iff high words of first 64 putative int64 values are all zero
__global__ void detect_kernel(const unsigned int* __restrict__ ei32, int* __restrict__ flag) {
    unsigned int v = ei32[2 * threadIdx.x + 1];
    unsigned long long nz = __ballot(v != 0u);
    if (threadIdx.x == 0) *flag = (nz == 0ULL) ? 1 : 0;
}

// K1: H = X @ W.T + per-node attention scalars.
// 256 thr: cg = t&15 (4 cols), rg = t>>4 (4 rows) -> 4x4 micro-tile, 64-row block tile.
__global__ __launch_bounds__(256) void gemm_kernel(
        const float* __restrict__ X, const float* __restrict__ W,
        const float* __restrict__ a_src, const float* __restrict__ a_dst,
        float* __restrict__ H, float* __restrict__ s_src, float* __restrict__ s_dst) {
    __shared__ float sWt[IN_DIM][OUT_DIM];   // 32 KB, k-major
    __shared__ float sX[64][65];             // 16.6 KB, k-major, pad 65
    const int t = threadIdx.x;
    const int row0 = blockIdx.x * 64;
    const int cg = t & 15;
    const int rg = t >> 4;

    for (int i = t; i < 64 * 32; i += 256) {
        int col = i & 63, k4 = i >> 6;
        float4 w = reinterpret_cast<const float4*>(W)[col * 32 + k4];
        sWt[4 * k4 + 0][col] = w.x;
        sWt[4 * k4 + 1][col] = w.y;
        sWt[4 * k4 + 2][col] = w.z;
        sWt[4 * k4 + 3][col] = w.w;
    }

    float acc[4][4];
    #pragma unroll
    for (int i = 0; i < 4; ++i)
        #pragma unroll
        for (int j = 0; j < 4; ++j) acc[i][j] = 0.f;

    #pragma unroll
    for (int kk = 0; kk < 2; ++kk) {
        const int kb = kk * 64;
        __syncthreads();
        for (int i = t; i < 64 * 16; i += 256) {
            int k4 = i & 15, row = i >> 4;
            int grow = row0 + row;
            float4 x = make_float4(0.f, 0.f, 0.f, 0.f);
            if (grow < N_NODES)
                x = reinterpret_cast<const float4*>(X)[(size_t)grow * 32 + (kb >> 2) + k4];
            sX[4 * k4 + 0][row] = x.x;
            sX[4 * k4 + 1][row] = x.y;
            sX[4 * k4 + 2][row] = x.z;
            sX[4 * k4 + 3][row] = x.w;
        }
        __syncthreads();
        #pragma unroll 4
        for (int k = 0; k < 64; ++k) {
            float4 wv = *reinterpret_cast<const float4*>(&sWt[kb + k][cg * 4]);
            #pragma unroll
            for (int i = 0; i < 4; ++i) {
                float xv = sX[k][rg * 4 + i];
                acc[i][0] += xv * wv.x; acc[i][1] += xv * wv.y;
                acc[i][2] += xv * wv.z; acc[i][3] += xv * wv.w;
            }
        }
    }

    float4 as = *reinterpret_cast<const float4*>(&a_src[cg * 4]);
    float4 ad = *reinterpret_cast<const float4*>(&a_dst[cg * 4]);
    #pragma unroll
    for (int i = 0; i < 4; ++i) {
        float ps = acc[i][0] * as.x + acc[i][1] * as.y + acc[i][2] * as.z + acc[i][3] * as.w;
        float pd = acc[i][0] * ad.x + acc[i][1] * ad.y + acc[i][2] * ad.z + acc[i][3] * ad.w;
        #pragma unroll
        for (int off = 1; off < 16; off <<= 1) {
            ps += __shfl_xor(ps, off);
            pd += __shfl_xor(pd, off);
        }
        int row = row0 + rg * 4 + i;
        if (row < N_NODES) {
            *reinterpret_cast<float4*>(&H[(size_t)row * OUT_DIM + cg * 4]) =
                make_float4(acc[i][0], acc[i][1], acc[i][2], acc[i][3]);
            if (cg == 0) { s_src[row] = ps; s_dst[row] = pd; }
        }
    }
}

// K2: packed = dst<<16|src; degree histogram; per-block max (NO global atomicMax:
// 12.5k same-address atomics serialized ~12ns each = the 155us stall last round)
__global__ __launch_bounds__(256) void edge_pack_count_kernel(
        const void* __restrict__ ei, const int* __restrict__ flag,
        const float* __restrict__ s_src, const float* __restrict__ s_dst,
        unsigned int* __restrict__ packed, int* __restrict__ count,
        float* __restrict__ blockmax) {
    const int use64 = *flag;
    const int i = blockIdx.x * 256 + threadIdx.x;      // grid exact: no bounds check
    int s = eidx(ei, use64, i);
    int d = eidx(ei, use64, (long long)N_EDGES + i);
    float v = s_src[s] + s_dst[d];
    v = (v >= 0.f) ? v : NEG_SLOPE * v;
    packed[i] = ((unsigned int)d << 16) | (unsigned int)s;
    atomicAdd(&count[d], 1);
    #pragma unroll
    for (int off = 32; off; off >>= 1) v = fmaxf(v, __shfl_xor(v, off));
    __shared__ float wmax[4];
    if ((threadIdx.x & 63) == 0) wmax[threadIdx.x >> 6] = v;
    __syncthreads();
    if (threadIdx.x == 0)
        blockmax[blockIdx.x] = fmaxf(fmaxf(wmax[0], wmax[1]), fmaxf(wmax[2], wmax[3]));
}

// KM: single-block max reduction over blockmax[NBLK_E]
__global__ __launch_bounds__(256) void max_reduce_kernel(
        const float* __restrict__ blockmax, float* __restrict__ gmax) {
    float v = -3.402823466e38f;
    for (int i = threadIdx.x; i < NBLK_E; i += 256) v = fmaxf(v, blockmax[i]);
    #pragma unroll
    for (int off = 32; off; off >>= 1) v = fmaxf(v, __shfl_xor(v, off));
    __shared__ float wmax[4];
    if ((threadIdx.x & 63) == 0) wmax[threadIdx.x >> 6] = v;
    __syncthreads();
    if (threadIdx.x == 0)
        *gmax = fmaxf(fmaxf(wmax[0], wmax[1]), fmaxf(wmax[2], wmax[3]));
}

// ---- hierarchical exclusive scan of count[N] -> rowstart, cursor ----
__device__ __forceinline__ int block_excl_scan_256(int x, int* lds4) {
    const int lane = threadIdx.x & 63;
    const int wid  = threadIdx.x >> 6;
    int incl = x;
    #pragma unroll
    for (int off = 1; off < 64; off <<= 1) {
        int n = __shfl_up(incl, off);
        if (lane >= off) incl += n;
    }
    if (lane == 63) lds4[wid] = incl;
    __syncthreads();
    if (threadIdx.x == 0) {
        int s = 0;
        #pragma unroll
        for (int w = 0; w < 4; ++w) { int tv = lds4[w]; lds4[w] = s; s += tv; }
    }
    __syncthreads();
    return lds4[wid] + incl - x;
}

__global__ __launch_bounds__(256) void scan1_kernel(const int* __restrict__ count,
                                                    int* __restrict__ blockSum) {
    int i = blockIdx.x * 256 + threadIdx.x;
    int v = (i < N_NODES) ? count[i] : 0;
    #pragma unroll
    for (int off = 32; off; off >>= 1) v += __shfl_xor(v, off);
    __shared__ int lds4[4];
    if ((threadIdx.x & 63) == 0) lds4[threadIdx.x >> 6] = v;
    __syncthreads();
    if (threadIdx.x == 0) blockSum[blockIdx.x] = lds4[0] + lds4[1] + lds4[2] + lds4[3];
}

__global__ __launch_bounds__(256) void scan2_kernel(int* __restrict__ blockSum) {
    __shared__ int lds4[4];
    int v = (threadIdx.x < NBLK_SCAN) ? blockSum[threadIdx.x] : 0;
    int ex = block_excl_scan_256(v, lds4);
    if (threadIdx.x < NBLK_SCAN) blockSum[threadIdx.x] = ex;
}

__global__ __launch_bounds__(256) void scan3_kernel(const int* __restrict__ count,
                                                    const int* __restrict__ blockOfs,
                                                    int* __restrict__ rowstart,
                                                    int* __restrict__ cursor) {
    __shared__ int lds4[4];
    int i = blockIdx.x * 256 + threadIdx.x;
    int v = (i < N_NODES) ? count[i] : 0;
    int ex = block_excl_scan_256(v, lds4) + blockOfs[blockIdx.x];
    if (i < N_NODES) { rowstart[i] = ex; cursor[i] = ex; }
}

// KF: bucket edges into CSR order (src only, 16-bit)
__global__ __launch_bounds__(256) void fill_kernel(
        const unsigned int* __restrict__ packed, int* __restrict__ cursor,
        unsigned short* __restrict__ csr16) {
    const int i = blockIdx.x * 256 + threadIdx.x;      // grid exact
    unsigned int p = packed[i];
    int d = p >> 16;
    int pos = atomicAdd(&cursor[d], 1);
    csr16[pos] = (unsigned short)(p & 0xFFFFu);
}

// KA: one wave per dst. lane = (eo = lane>>4, cg = lane&15): 4 edges in flight,
// 16 lanes x float4 per H row. w recomputed from s_src/s_dst (kills csr_w array).
__global__ __launch_bounds__(256) void aggregate_kernel(
        const float* __restrict__ H, const float* __restrict__ s_src,
        const float* __restrict__ s_dst, const float* __restrict__ gmaxp,
        const int* __restrict__ count, const int* __restrict__ rowstart,
        const unsigned short* __restrict__ csr16, float* __restrict__ out) {
    const float gmax = *gmaxp;
    const int lane = threadIdx.x & 63;
    const int eo   = lane >> 4;
    const int cg   = lane & 15;
    const int dst  = blockIdx.x * 4 + (threadIdx.x >> 6);   // grid exact: 12500*4
    const int rs  = rowstart[dst];
    const int deg = count[dst];
    const float sd = s_dst[dst];
    float4 acc = make_float4(0.f, 0.f, 0.f, 0.f);
    float denom = 0.f;
    for (int j = 0; j < deg; j += 4) {
        int jj = j + eo;
        int s = 0;
        float w = 0.f;
        if (jj < deg) {
            s = csr16[rs + jj];                 // 16-lane broadcast
            float t = s_src[s] + sd;            // s_src: L2-resident gather
            t = (t >= 0.f) ? t : NEG_SLOPE * t;
            w = expf(t - gmax);
        }
        float4 h = *reinterpret_cast<const float4*>(&H[(size_t)s * OUT_DIM + cg * 4]);
        acc.x += w * h.x; acc.y += w * h.y; acc.z += w * h.z; acc.w += w * h.w;
        denom += w;
    }
    acc.x += __shfl_xor(acc.x, 16); acc.y += __shfl_xor(acc.y, 16);
    acc.z += __shfl_xor(acc.z, 16); acc.w += __shfl_xor(acc.w, 16);
    denom += __shfl_xor(denom, 16);
    acc.x += __shfl_xor(acc.x, 32); acc.y += __shfl_xor(acc.y, 32);
    acc.z += __shfl_xor(acc.z, 32); acc.w += __shfl_xor(acc.w, 32);
    denom += __shfl_xor(denom, 32);
    if (eo == 0) {
        float inv = 1.f / (denom + 1e-12f);
        *reinterpret_cast<float4*>(&out[(size_t)dst * OUT_DIM + cg * 4]) =
            make_float4(acc.x * inv, acc.y * inv, acc.z * inv, acc.w * inv);
    }
}

extern "C" void kernel_launch(void* const* d_in, const int* in_sizes, int n_in,
                              void* d_out, int out_size, void* d_ws, size_t ws_size,
                              hipStream_t stream) {
    const float* X     = (const float*)d_in[0];
    const void*  ei    = d_in[1];                 // [2,E] int32 or int64 (detected)
    const float* W     = (const float*)d_in[3];
    const float* a_src = (const float*)d_in[4];
    const float* a_dst = (const float*)d_in[5];
    float* out = (float*)d_out;

    float* ws      = (float*)d_ws;
    float* H       = ws + WS_H;
    float* s_src   = ws + WS_SSRC;
    float* s_dst   = ws + WS_SDST;
    unsigned int* packed = (unsigned int*)(ws + WS_PACK);
    int*   count   = (int*)(ws + WS_COUNT);
    float* gmax    = ws + WS_GMAX;
    int*   flag    = (int*)(ws + WS_FLAG);
    int*   rowst   = (int*)(ws + WS_ROWST);
    int*   cursor  = (int*)(ws + WS_CURS);
    int*   bsum    = (int*)(ws + WS_BSUM);
    float* bmax    = ws + WS_BMAX;
    unsigned short* csr16 = (unsigned short*)(ws + WS_CSR16);

    hipMemsetAsync(count, 0, (size_t)N_NODES * sizeof(int), stream);

    detect_kernel<<<1, 64, 0, stream>>>((const unsigned int*)ei, flag);
    gemm_kernel<<<(N_NODES + 63) / 64, 256, 0, stream>>>(X, W, a_src, a_dst, H, s_src, s_dst);
    edge_pack_count_kernel<<<NBLK_E, 256, 0, stream>>>(ei, flag, s_src, s_dst, packed, count, bmax);
    max_reduce_kernel<<<1, 256, 0, stream>>>(bmax, gmax);
    scan1_kernel<<<NBLK_SCAN, 256, 0, stream>>>(count, bsum);
    scan2_kernel<<<1, 256, 0, stream>>>(bsum);
    scan3_kernel<<<NBLK_SCAN, 256, 0, stream>>>(count, bsum, rowst, cursor);
    fill_kernel<<<NBLK_E, 256, 0, stream>>>(packed, cursor, csr16);
    aggregate_kernel<<<N_NODES / 4, 256, 0, stream>>>(H, s_src, s_dst, gmax, count, rowst, csr16, out);
}

// Round 5
// 222.730 us; speedup vs baseline: 1.5924x; 1.0576x over previous
//
#include <hip/hip_runtime.h>

// GAT layer, CSR formulation, no single-address atomics, no max-shift
// (softmax is exactly shift-invariant; e = s_src+s_dst is O(5) so exp() is safe):
//   K1  GEMM X@W.T -> H  (64-row tile, 4x4 micro-tile; b128 LDS reads both operands;
//       fused s_src[n]=H[n]·a_src, s_dst[n]=H[n]·a_dst)
//   K2  packed[i]=dst<<16|src; count[dst]++   (edge-width detect inlined)
//   S1-S3  exclusive scan of counts -> rowstart, cursor
//   KF  pos=atomicAdd(cursor[dst]); csr16[pos]=src  (ushort)
//   KA  one wave per dst, 8 edges in flight x 16 lanes x float4; w=exp(lrelu(...)).

#define N_NODES 50000
#define N_EDGES 800000
#define IN_DIM  128
#define OUT_DIM 64
#define NEG_SLOPE 0.2f
#define NBLK_SCAN ((N_NODES + 255) / 256)   // 196
#define NBLK_E    (N_EDGES / 256)           // 3125 exact

// workspace layout (4-byte element offsets)
#define WS_H      0                          // float N*64
#define WS_SSRC   (N_NODES * OUT_DIM)        // float N
#define WS_SDST   (WS_SSRC + N_NODES)        // float N
#define WS_PACK   (WS_SDST + N_NODES)        // uint E
#define WS_COUNT  (WS_PACK + N_EDGES)        // int N   (memset 0)
#define WS_ROWST  (WS_COUNT + N_NODES)       // int N
#define WS_CURS   (WS_ROWST + N_NODES)       // int N
#define WS_BSUM   (WS_CURS + N_NODES)        // int 256
#define WS_CSR16  (WS_BSUM + 256)            // ushort E

// uniform-branch edge index fetch (int32 or int64 storage)
__device__ __forceinline__ int eidx(const void* ei, int use64, long long i) {
    return use64 ? (int)((const long long*)ei)[i] : ((const int*)ei)[i];
}

// K1: H = X @ W.T + per-node attention scalars.
// 256 thr: cg = t&15 (4 cols), rg = t>>4 (4 rows) -> 4x4 micro-tile, 64-row tile.
// Both LDS operands k-major; X pad 76 (304B stride: 16B-aligned for b128,
// staging-write banks spread ~2-way = free; inner reads broadcast, conflict-free).
__global__ __launch_bounds__(256) void gemm_kernel(
        const float* __restrict__ X, const float* __restrict__ W,
        const float* __restrict__ a_src, const float* __restrict__ a_dst,
        float* __restrict__ H, float* __restrict__ s_src, float* __restrict__ s_dst) {
    __shared__ float sWt[IN_DIM][OUT_DIM];   // 32 KB
    __shared__ float sX[64][76];             // 19 KB; 51 KB total -> 3 blocks/CU
    const int t = threadIdx.x;
    const int row0 = blockIdx.x * 64;
    const int cg = t & 15;
    const int rg = t >> 4;

    for (int i = t; i < 64 * 32; i += 256) {
        int col = i & 63, k4 = i >> 6;
        float4 w = reinterpret_cast<const float4*>(W)[col * 32 + k4];
        sWt[4 * k4 + 0][col] = w.x;
        sWt[4 * k4 + 1][col] = w.y;
        sWt[4 * k4 + 2][col] = w.z;
        sWt[4 * k4 + 3][col] = w.w;
    }

    float acc[4][4];
    #pragma unroll
    for (int i = 0; i < 4; ++i)
        #pragma unroll
        for (int j = 0; j < 4; ++j) acc[i][j] = 0.f;

    #pragma unroll
    for (int kk = 0; kk < 2; ++kk) {
        const int kb = kk * 64;
        __syncthreads();
        for (int i = t; i < 64 * 16; i += 256) {
            int k4 = i & 15, row = i >> 4;
            int grow = row0 + row;
            float4 x = make_float4(0.f, 0.f, 0.f, 0.f);
            if (grow < N_NODES)
                x = reinterpret_cast<const float4*>(X)[(size_t)grow * 32 + (kb >> 2) + k4];
            sX[4 * k4 + 0][row] = x.x;
            sX[4 * k4 + 1][row] = x.y;
            sX[4 * k4 + 2][row] = x.z;
            sX[4 * k4 + 3][row] = x.w;
        }
        __syncthreads();
        #pragma unroll 4
        for (int k = 0; k < 64; ++k) {
            float4 wv = *reinterpret_cast<const float4*>(&sWt[kb + k][cg * 4]);  // b128
            float4 xv = *reinterpret_cast<const float4*>(&sX[k][rg * 4]);        // b128
            acc[0][0] += xv.x * wv.x; acc[0][1] += xv.x * wv.y;
            acc[0][2] += xv.x * wv.z; acc[0][3] += xv.x * wv.w;
            acc[1][0] += xv.y * wv.x; acc[1][1] += xv.y * wv.y;
            acc[1][2] += xv.y * wv.z; acc[1][3] += xv.y * wv.w;
            acc[2][0] += xv.z * wv.x; acc[2][1] += xv.z * wv.y;
            acc[2][2] += xv.z * wv.z; acc[2][3] += xv.z * wv.w;
            acc[3][0] += xv.w * wv.x; acc[3][1] += xv.w * wv.y;
            acc[3][2] += xv.w * wv.z; acc[3][3] += xv.w * wv.w;
        }
    }

    float4 as = *reinterpret_cast<const float4*>(&a_src[cg * 4]);
    float4 ad = *reinterpret_cast<const float4*>(&a_dst[cg * 4]);
    #pragma unroll
    for (int i = 0; i < 4; ++i) {
        float ps = acc[i][0] * as.x + acc[i][1] * as.y + acc[i][2] * as.z + acc[i][3] * as.w;
        float pd = acc[i][0] * ad.x + acc[i][1] * ad.y + acc[i][2] * ad.z + acc[i][3] * ad.w;
        #pragma unroll
        for (int off = 1; off < 16; off <<= 1) {
            ps += __shfl_xor(ps, off);
            pd += __shfl_xor(pd, off);
        }
        int row = row0 + rg * 4 + i;
        if (row < N_NODES) {
            *reinterpret_cast<float4*>(&H[(size_t)row * OUT_DIM + cg * 4]) =
                make_float4(acc[i][0], acc[i][1], acc[i][2], acc[i][3]);
            if (cg == 0) { s_src[row] = ps; s_dst[row] = pd; }
        }
    }
}

// K2: packed = dst<<16|src; degree histogram. Edge-width detection inlined
// (wave 0 inspects high words of the first 64 putative int64s; same 512B
// every block -> L2 broadcast).
__global__ __launch_bounds__(256) void edge_pack_count_kernel(
        const void* __restrict__ ei, unsigned int* __restrict__ packed,
        int* __restrict__ count) {
    __shared__ int s_use64;
    if (threadIdx.x < 64) {
        unsigned int v = ((const unsigned int*)ei)[2 * threadIdx.x + 1];
        unsigned long long nz = __ballot(v != 0u);
        if (threadIdx.x == 0) s_use64 = (nz == 0ULL) ? 1 : 0;
    }
    __syncthreads();
    const int use64 = s_use64;
    const int i = blockIdx.x * 256 + threadIdx.x;      // grid exact
    int s = eidx(ei, use64, i);
    int d = eidx(ei, use64, (long long)N_EDGES + i);
    packed[i] = ((unsigned int)d << 16) | (unsigned int)s;
    atomicAdd(&count[d], 1);
}

// ---- hierarchical exclusive scan of count[N] -> rowstart, cursor ----
__device__ __forceinline__ int block_excl_scan_256(int x, int* lds4) {
    const int lane = threadIdx.x & 63;
    const int wid  = threadIdx.x >> 6;
    int incl = x;
    #pragma unroll
    for (int off = 1; off < 64; off <<= 1) {
        int n = __shfl_up(incl, off);
        if (lane >= off) incl += n;
    }
    if (lane == 63) lds4[wid] = incl;
    __syncthreads();
    if (threadIdx.x == 0) {
        int s = 0;
        #pragma unroll
        for (int w = 0; w < 4; ++w) { int tv = lds4[w]; lds4[w] = s; s += tv; }
    }
    __syncthreads();
    return lds4[wid] + incl - x;
}

__global__ __launch_bounds__(256) void scan1_kernel(const int* __restrict__ count,
                                                    int* __restrict__ blockSum) {
    int i = blockIdx.x * 256 + threadIdx.x;
    int v = (i < N_NODES) ? count[i] : 0;
    #pragma unroll
    for (int off = 32; off; off >>= 1) v += __shfl_xor(v, off);
    __shared__ int lds4[4];
    if ((threadIdx.x & 63) == 0) lds4[threadIdx.x >> 6] = v;
    __syncthreads();
    if (threadIdx.x == 0) blockSum[blockIdx.x] = lds4[0] + lds4[1] + lds4[2] + lds4[3];
}

__global__ __launch_bounds__(256) void scan2_kernel(int* __restrict__ blockSum) {
    __shared__ int lds4[4];
    int v = (threadIdx.x < NBLK_SCAN) ? blockSum[threadIdx.x] : 0;
    int ex = block_excl_scan_256(v, lds4);
    if (threadIdx.x < NBLK_SCAN) blockSum[threadIdx.x] = ex;
}

__global__ __launch_bounds__(256) void scan3_kernel(const int* __restrict__ count,
                                                    const int* __restrict__ blockOfs,
                                                    int* __restrict__ rowstart,
                                                    int* __restrict__ cursor) {
    __shared__ int lds4[4];
    int i = blockIdx.x * 256 + threadIdx.x;
    int v = (i < N_NODES) ? count[i] : 0;
    int ex = block_excl_scan_256(v, lds4) + blockOfs[blockIdx.x];
    if (i < N_NODES) { rowstart[i] = ex; cursor[i] = ex; }
}

// KF: bucket edges into CSR order (src only, 16-bit)
__global__ __launch_bounds__(256) void fill_kernel(
        const unsigned int* __restrict__ packed, int* __restrict__ cursor,
        unsigned short* __restrict__ csr16) {
    const int i = blockIdx.x * 256 + threadIdx.x;      // grid exact
    unsigned int p = packed[i];
    int d = p >> 16;
    int pos = atomicAdd(&cursor[d], 1);
    csr16[pos] = (unsigned short)(p & 0xFFFFu);
}

// KA: one wave per dst. lane = (eo = lane>>4, cg = lane&15); 8 edges in flight
// (2 x 4-edge groups per iter). w recomputed from s_src/s_dst, no max shift.
__global__ __launch_bounds__(256) void aggregate_kernel(
        const float* __restrict__ H, const float* __restrict__ s_src,
        const float* __restrict__ s_dst, const int* __restrict__ count,
        const int* __restrict__ rowstart, const unsigned short* __restrict__ csr16,
        float* __restrict__ out) {
    const int lane = threadIdx.x & 63;
    const int eo   = lane >> 4;
    const int cg   = lane & 15;
    const int dst  = blockIdx.x * 4 + (threadIdx.x >> 6);   // grid exact
    const int rs  = rowstart[dst];
    const int deg = count[dst];
    const float sd = s_dst[dst];
    float4 acc = make_float4(0.f, 0.f, 0.f, 0.f);
    float denom = 0.f;
    for (int j = 0; j < deg; j += 8) {
        int jj0 = j + eo, jj1 = j + 4 + eo;
        int s0 = 0, s1 = 0;
        float w0 = 0.f, w1 = 0.f;
        if (jj0 < deg) {
            s0 = csr16[rs + jj0];
            float t0 = s_src[s0] + sd;
            t0 = (t0 >= 0.f) ? t0 : NEG_SLOPE * t0;
            w0 = expf(t0);
        }
        if (jj1 < deg) {
            s1 = csr16[rs + jj1];
            float t1 = s_src[s1] + sd;
            t1 = (t1 >= 0.f) ? t1 : NEG_SLOPE * t1;
            w1 = expf(t1);
        }
        float4 h0 = *reinterpret_cast<const float4*>(&H[(size_t)s0 * OUT_DIM + cg * 4]);
        float4 h1 = *reinterpret_cast<const float4*>(&H[(size_t)s1 * OUT_DIM + cg * 4]);
        acc.x += w0 * h0.x + w1 * h1.x;
        acc.y += w0 * h0.y + w1 * h1.y;
        acc.z += w0 * h0.z + w1 * h1.z;
        acc.w += w0 * h0.w + w1 * h1.w;
        denom += w0 + w1;
    }
    acc.x += __shfl_xor(acc.x, 16); acc.y += __shfl_xor(acc.y, 16);
    acc.z += __shfl_xor(acc.z, 16); acc.w += __shfl_xor(acc.w, 16);
    denom += __shfl_xor(denom, 16);
    acc.x += __shfl_xor(acc.x, 32); acc.y += __shfl_xor(acc.y, 32);
    acc.z += __shfl_xor(acc.z, 32); acc.w += __shfl_xor(acc.w, 32);
    denom += __shfl_xor(denom, 32);
    if (eo == 0) {
        float inv = 1.f / (denom + 1e-12f);
        *reinterpret_cast<float4*>(&out[(size_t)dst * OUT_DIM + cg * 4]) =
            make_float4(acc.x * inv, acc.y * inv, acc.z * inv, acc.w * inv);
    }
}

extern "C" void kernel_launch(void* const* d_in, const int* in_sizes, int n_in,
                              void* d_out, int out_size, void* d_ws, size_t ws_size,
                              hipStream_t stream) {
    const float* X     = (const float*)d_in[0];
    const void*  ei    = d_in[1];                 // [2,E] int32 or int64 (detected)
    const float* W     = (const float*)d_in[3];
    const float* a_src = (const float*)d_in[4];
    const float* a_dst = (const float*)d_in[5];
    float* out = (float*)d_out;

    float* ws      = (float*)d_ws;
    float* H       = ws + WS_H;
    float* s_src   = ws + WS_SSRC;
    float* s_dst   = ws + WS_SDST;
    unsigned int* packed = (unsigned int*)(ws + WS_PACK);
    int*   count   = (int*)(ws + WS_COUNT);
    int*   rowst   = (int*)(ws + WS_ROWST);
    int*   cursor  = (int*)(ws + WS_CURS);
    int*   bsum    = (int*)(ws + WS_BSUM);
    unsigned short* csr16 = (unsigned short*)(ws + WS_CSR16);

    hipMemsetAsync(count, 0, (size_t)N_NODES * sizeof(int), stream);

    gemm_kernel<<<(N_NODES + 63) / 64, 256, 0, stream>>>(X, W, a_src, a_dst, H, s_src, s_dst);
    edge_pack_count_kernel<<<NBLK_E, 256, 0, stream>>>(ei, packed, count);
    scan1_kernel<<<NBLK_SCAN, 256, 0, stream>>>(count, bsum);
    scan2_kernel<<<1, 256, 0, stream>>>(bsum);
    scan3_kernel<<<NBLK_SCAN, 256, 0, stream>>>(count, bsum, rowst, cursor);
    fill_kernel<<<NBLK_E, 256, 0, stream>>>(packed, cursor, csr16);
    aggregate_kernel<<<N_NODES / 4, 256, 0, stream>>>(H, s_src, s_dst, count, rowst, csr16, out);
}